// Round 3
// baseline (434.378 us; speedup 1.0000x reference)
//
#include <hip/hip_runtime.h>
#include <cstdint>
#include <cstddef>

typedef __bf16 bf16_t;
typedef __bf16 bf16x8 __attribute__((ext_vector_type(8)));
typedef __bf16 bf16x4 __attribute__((ext_vector_type(4)));
typedef float floatx4 __attribute__((ext_vector_type(4)));

#define B_  2
#define T_  2048
#define C_  2048
#define H_  16
#define HD_ 128

// 1/sqrt(128) * log2(e) — folded into Q at QKV-GEMM epilogue
#define K_ATTN_SCALE (0.08838834764831843f * 1.44269504088896f)

// ---- async global->LDS, 16B per lane (m97 recipe) ----
__device__ __forceinline__ void async_copy16(const void* g, void* l) {
  __builtin_amdgcn_global_load_lds((const __attribute__((address_space(1))) unsigned int*)g,
                                   (__attribute__((address_space(3))) unsigned int*)l,
                                   16, 0, 0);
}

// ---------------- convert fp32 -> bf16 (flat) ----------------
__global__ __launch_bounds__(256) void cvt_f32_bf16(const float* __restrict__ in,
                                                    bf16_t* __restrict__ out, int n4) {
  int i = blockIdx.x * 256 + threadIdx.x;
  if (i >= n4) return;
  const float4 v = ((const float4*)in)[i];
  bf16x4 o;
  o[0] = (bf16_t)v.x; o[1] = (bf16_t)v.y; o[2] = (bf16_t)v.z; o[3] = (bf16_t)v.w;
  ((bf16x4*)out)[i] = o;
}

// ------- transpose + convert: W[Kd][Nd] fp32 -> Wt[Nd][Kd] bf16 -------
__global__ __launch_bounds__(256) void transpose_cvt(const float* __restrict__ W,
                                                     bf16_t* __restrict__ Wt,
                                                     int Kd, int Nd) {
  __shared__ float tile[32][33];
  const int tx = threadIdx.x, ty = threadIdx.y;
  const int n0 = blockIdx.x * 32, k0 = blockIdx.y * 32;
#pragma unroll
  for (int j = ty; j < 32; j += 8)
    tile[j][tx] = W[(size_t)(k0 + j) * Nd + n0 + tx];
  __syncthreads();
#pragma unroll
  for (int j = ty; j < 32; j += 8)
    Wt[(size_t)(n0 + j) * Kd + k0 + tx] = (bf16_t)tile[tx][j];
}

// =====================================================================
// QKV GEMM — 256x256 tile, 8 waves, BK=32, TRIPLE-buffered LDS (96 KiB of
// the 128 KiB block), 2-tile-ahead prefetch, COUNTED vmcnt(4) at tile end
// (never 0 in main loop). 2 phases/tile, 16 MFMA each; B-frags loaded once
// per tile (12 ds_read_b128/wave/tile). Swizzle: slot ^= (row&3).
// =====================================================================
#define GBM 256
#define GBN 256
#define GBK 32

__global__ __launch_bounds__(512, 2) void gemm_qkv(
    const bf16_t* __restrict__ A, const bf16_t* __restrict__ Bt,
    const float* __restrict__ bias,
    bf16_t* __restrict__ Qo, bf16_t* __restrict__ Ko, bf16_t* __restrict__ Vo,
    int K) {
  __shared__ __align__(16) char smem[131072];   // 3 bufs x 32KB used by loop; all 128KB by V-epilogue
  const int tid = threadIdx.x;
  const int wave = tid >> 6, lane = tid & 63;
  const int quad = lane >> 4, l15 = lane & 15;
  const int wm = wave >> 2, wn = wave & 3;
  const int bm = blockIdx.y * GBM, bn = blockIdx.x * GBN;

  // ---- staging map: linear LDS dest <- inverse-swizzled global source ----
  // per operand tile 16KB: p = l*8192 + tid*16; row r = p>>6 (64B rows),
  // slot = (p>>4)&3 holds logical slot slot^(r&3).
  const bf16_t* asrc[2];
  const bf16_t* bsrc[2];
#pragma unroll
  for (int l = 0; l < 2; ++l) {
    int p = l * 8192 + tid * 16;
    int r = p >> 6;
    int c = ((p >> 4) & 3) ^ (r & 3);           // logical 16B slot
    asrc[l] = A  + (size_t)(bm + r) * K + c * 8;
    bsrc[l] = Bt + (size_t)(bn + r) * K + c * 8;
  }

  auto stageA = [&](int buf, int k0) {
    char* As = smem + buf * 32768;
#pragma unroll
    for (int l = 0; l < 2; ++l)
      async_copy16(asrc[l] + k0, As + l * 8192 + tid * 16);
  };
  auto stageB = [&](int buf, int k0) {
    char* Bs = smem + buf * 32768 + 16384;
#pragma unroll
    for (int l = 0; l < 2; ++l)
      async_copy16(bsrc[l] + k0, Bs + l * 8192 + tid * 16);
  };

  // ---- read-side swizzle: 16B slot ^= (row&3); row&3 == l15&3 (fragment rows
  //      step by 16) -> per-thread constant.
  const int sx = (l15 & 3) << 4;
  const int cq = quad * 16;                 // k-slot byte base
  const int arow = (wm * 128 + l15) * 64;   // A row byte base (+ i*16 rows)
  const int brow = (wn * 64 + l15) * 64;    // B row byte base (+ j*16 rows)

  floatx4 acc[8][4] = {};
  bf16x8 af[8], bfr[4];

  // ---- prologue: prime 2 tiles ----
  stageA(0, 0); stageB(0, 0);
  stageA(1, GBK); stageB(1, GBK);
  asm volatile("s_waitcnt vmcnt(4)" ::: "memory");   // buf0 complete; buf1 in flight
  __builtin_amdgcn_s_barrier();

  const int NT = K / GBK;   // 64
  int cur = 0;
  for (int t = 0; t < NT; ++t) {
    const char* As = smem + cur * 32768;
    const char* Bs = As + 16384;
    int nxt = cur + 2; if (nxt >= 3) nxt -= 3;
    const bool st = (t + 2 < NT);

    // -------- phase 0: bfr[0..3] + af[0..3]; stage A-half of t+2 --------
#pragma unroll
    for (int j = 0; j < 4; ++j)
      bfr[j] = *(const bf16x8*)(Bs + brow + j * 16 * 64 + (cq ^ sx));
#pragma unroll
    for (int i = 0; i < 4; ++i)
      af[i] = *(const bf16x8*)(As + arow + i * 16 * 64 + (cq ^ sx));
    if (st) stageA(nxt, (t + 2) * GBK);
    __builtin_amdgcn_sched_barrier(0);
    __builtin_amdgcn_s_barrier();
    asm volatile("s_waitcnt lgkmcnt(0)" ::: "memory");
    __builtin_amdgcn_sched_barrier(0);
    __builtin_amdgcn_s_setprio(1);
#pragma unroll
    for (int i = 0; i < 4; ++i)
#pragma unroll
      for (int j = 0; j < 4; ++j)
        acc[i][j] = __builtin_amdgcn_mfma_f32_16x16x32_bf16(af[i], bfr[j], acc[i][j], 0, 0, 0);
    __builtin_amdgcn_s_setprio(0);
    __builtin_amdgcn_sched_barrier(0);
    __builtin_amdgcn_s_barrier();

    // -------- phase 1: af[4..7]; stage B-half of t+2 --------
#pragma unroll
    for (int i = 4; i < 8; ++i)
      af[i] = *(const bf16x8*)(As + arow + i * 16 * 64 + (cq ^ sx));
    if (st) stageB(nxt, (t + 2) * GBK);
    __builtin_amdgcn_sched_barrier(0);
    __builtin_amdgcn_s_barrier();
    asm volatile("s_waitcnt lgkmcnt(0)" ::: "memory");
    __builtin_amdgcn_sched_barrier(0);
    __builtin_amdgcn_s_setprio(1);
#pragma unroll
    for (int i = 4; i < 8; ++i)
#pragma unroll
      for (int j = 0; j < 4; ++j)
        acc[i][j] = __builtin_amdgcn_mfma_f32_16x16x32_bf16(af[i], bfr[j], acc[i][j], 0, 0, 0);
    __builtin_amdgcn_s_setprio(0);
    __builtin_amdgcn_sched_barrier(0);

    // -------- tile-end counted wait: drain t+1's loads, keep t+2's flying --------
    if (t < NT - 2) {
      asm volatile("s_waitcnt vmcnt(4)" ::: "memory");
    } else if (t == NT - 2) {
      asm volatile("s_waitcnt vmcnt(0)" ::: "memory");
    }
    __builtin_amdgcn_s_barrier();
    cur = cur + 1; if (cur >= 3) cur -= 3;
  }

  // ---------------- epilogue ----------------
  float bias_r[4];
#pragma unroll
  for (int j = 0; j < 4; ++j)
    bias_r[j] = bias[bn + wn * 64 + j * 16 + l15];

  if (bn < 2 * C_) {
    // ---- Q / K scatter to [B,H,T,hd] ----
    const int which = bn >> 11;  // 0 = Q, 1 = K (uniform per block)
    bf16_t* dst0 = which ? Ko : Qo;
    const float scl = which ? 1.0f : K_ATTN_SCALE;
#pragma unroll
    for (int i = 0; i < 8; ++i) {
      const int m = bm + wm * 128 + i * 16 + quad * 4;
      const int b = m >> 11, tq = m & 2047;
#pragma unroll
      for (int j = 0; j < 4; ++j) {
        const int n = bn + wn * 64 + j * 16 + l15;
        const int cc = n & 2047;
        const int h = cc >> 7, d = cc & 127;
        bf16_t* dst = dst0 + (((size_t)(b * H_ + h)) * T_ + tq) * HD_ + d;
#pragma unroll
        for (int r = 0; r < 4; ++r)
          dst[(size_t)r * HD_] = (bf16_t)((acc[i][j][r] + bias_r[j]) * scl);
      }
    }
  } else {
    // ---- V block: transpose 256x256 tile through LDS (full 128 KiB) ----
    __syncthreads();  // all waves fully past main-loop LDS reads
    bf16_t* vt = (bf16_t*)smem;
#pragma unroll
    for (int i = 0; i < 8; ++i) {
      const int tl = wm * 128 + i * 16 + quad * 4;
#pragma unroll
      for (int j = 0; j < 4; ++j) {
        const int dl = wn * 64 + j * 16 + l15;
        const int sw = 8 * (dl & 15);
#pragma unroll
        for (int r = 0; r < 4; ++r)
          vt[dl * 256 + ((tl + r) ^ sw)] = (bf16_t)(acc[i][j][r] + bias_r[j]);
      }
    }
    __syncthreads();
    const int dr = tid >> 1, half = tid & 1;
    const int h = ((bn - 2 * C_) >> 7) + (dr >> 7);
    const int b = bm >> 11, t0g = bm & 2047;
    bf16_t* dst = Vo + ((size_t)(b * H_ + h) * HD_ + (dr & 127)) * T_ + t0g;
#pragma unroll
    for (int cc2 = 0; cc2 < 16; ++cc2) {
      const int c = half * 16 + cc2;
      uint4 v = *(const uint4*)&vt[dr * 256 + ((c ^ (dr & 15)) * 8)];
      *(uint4*)(dst + c * 8) = v;
    }
  }
}

// ---------------- proj GEMM (m97 structure + XOR-swizzled LDS, fp32 out) ----------------
#define TM 128
#define TN 128
#define BK 64

__global__ __launch_bounds__(256) void gemm_proj(
    const bf16_t* __restrict__ A, const bf16_t* __restrict__ Bt,
    const float* __restrict__ bias, float* __restrict__ Cout,
    int M, int N, int K) {
  __shared__ __align__(16) char smem[32768];
  bf16_t (*As)[BK] = (bf16_t(*)[BK])smem;              // 16 KB
  bf16_t (*Bs)[BK] = (bf16_t(*)[BK])(smem + 16384);    // 16 KB
  const int tid = threadIdx.x;
  const int wave = tid >> 6, lane = tid & 63;
  const int quad = lane >> 4, l15 = lane & 15;
  const int bm = blockIdx.y * TM, bn = blockIdx.x * TN;
  const int wm = (wave >> 1) * 64, wn = (wave & 1) * 64;
  const int sw = l15 & 7;   // read-side swizzle

  floatx4 acc[4][4] = {};

  for (int k0 = 0; k0 < K; k0 += BK) {
#pragma unroll
    for (int it = 0; it < 4; ++it) {
      int p = it * 4096 + tid * 16;      // LDS byte offset (lane-linear)
      int r = p >> 7;                    // tile row
      int cg = ((p >> 4) & 7) ^ (r & 7); // global chunk held by this slot
      async_copy16(A + (size_t)(bm + r) * K + k0 + cg * 8, (char*)&As[0][0] + p);
      async_copy16(Bt + (size_t)(bn + r) * K + k0 + cg * 8, (char*)&Bs[0][0] + p);
    }
    __syncthreads();
#pragma unroll
    for (int kc = 0; kc < 2; ++kc) {
      const int cidx = (kc * 4 + quad) ^ sw;
      bf16x8 af[4], bf[4];
#pragma unroll
      for (int i = 0; i < 4; ++i)
        af[i] = *(const bf16x8*)&As[wm + i * 16 + l15][cidx * 8];
#pragma unroll
      for (int j = 0; j < 4; ++j)
        bf[j] = *(const bf16x8*)&Bs[wn + j * 16 + l15][cidx * 8];
#pragma unroll
      for (int i = 0; i < 4; ++i)
#pragma unroll
        for (int j = 0; j < 4; ++j)
          acc[i][j] = __builtin_amdgcn_mfma_f32_16x16x32_bf16(af[i], bf[j], acc[i][j], 0, 0, 0);
    }
    __syncthreads();
  }

#pragma unroll
  for (int i = 0; i < 4; ++i) {
#pragma unroll
    for (int j = 0; j < 4; ++j) {
#pragma unroll
      for (int r = 0; r < 4; ++r) {
        int m = bm + wm + i * 16 + quad * 4 + r;
        int n = bn + wn + j * 16 + l15;
        Cout[(size_t)m * N + n] = acc[i][j][r] + bias[n];
      }
    }
  }
}

// ---------------- causal flash attention (double-buffered K/V staging) ----------------
__global__ __launch_bounds__(256) void attn(const bf16_t* __restrict__ Q,
                                            const bf16_t* __restrict__ Kg,
                                            const bf16_t* __restrict__ Vt,
                                            bf16_t* __restrict__ O) {
  __shared__ bf16_t Ks[2][64][128];   // rows 256B=16 chunks; chunk c of row r at c^(r&15)
  __shared__ bf16_t Vs[2][128][64];   // rows 128B=8 chunks;  chunk c of row r at c^(r&7)
  const int tid = threadIdx.x;
  const int wave = tid >> 6, lane = tid & 63;
  const int quad = lane >> 4, l15 = lane & 15;
  const int j = blockIdx.x;        // 0..15
  const int bh = blockIdx.y;
  const int b = bh >> 4, h = bh & 15;
  const int qtA = 31 - j, qtB = j;           // heavy, light
  const int nchA = qtA + 1, nchB = qtB + 1;
  const int q0A = qtA * 64 + wave * 16;
  const int q0B = qtB * 64 + wave * 16;

  const bf16_t* Qh = Q + (size_t)bh * T_ * HD_;
  const bf16_t* Kh = Kg + (size_t)bh * T_ * HD_;
  const bf16_t* Vh = Vt + (size_t)bh * HD_ * T_;

  bf16x8 qfA[4], qfB[4];
#pragma unroll
  for (int kk = 0; kk < 4; ++kk) {
    qfA[kk] = *(const bf16x8*)(Qh + (size_t)(q0A + l15) * HD_ + kk * 32 + quad * 8);
    qfB[kk] = *(const bf16x8*)(Qh + (size_t)(q0B + l15) * HD_ + kk * 32 + quad * 8);
  }

  floatx4 oaccA[8] = {}, oaccB[8] = {};
  float l_A = 0.0f, l_B = 0.0f;

  union PU { bf16x4 v; long long u; };
  union PF { long long u[2]; bf16x8 v; };
  const int lo = ((lane & 16) << 1) + l15;  // (quad&1)*32 + l15

  auto stage = [&](int buf, int kt0) {
#pragma unroll
    for (int it = 0; it < 4; ++it) {
      int p = it * 4096 + tid * 16;
      int r = p >> 8;
      int cg = ((p >> 4) & 15) ^ (r & 15);
      async_copy16(Kh + (size_t)(kt0 + r) * HD_ + cg * 8, (char*)&Ks[buf][0][0] + p);
    }
#pragma unroll
    for (int it = 0; it < 4; ++it) {
      int p = it * 4096 + tid * 16;
      int r = p >> 7;
      int cg = ((p >> 4) & 7) ^ (r & 7);
      async_copy16(Vh + (size_t)r * T_ + kt0 + cg * 8, (char*)&Vs[buf][0][0] + p);
    }
  };

  auto step = [&](int buf, const bf16x8* qf, floatx4* oacc, float& l_i, int q0, int kt0,
                  bool mask) {
    floatx4 s[4] = {{}, {}, {}, {}};
#pragma unroll
    for (int st = 0; st < 4; ++st) {
#pragma unroll
      for (int kk = 0; kk < 4; ++kk) {
        bf16x8 kf = *(const bf16x8*)&Ks[buf][st * 16 + l15][(((kk * 4 + quad) ^ l15) & 15) * 8];
        s[st] = __builtin_amdgcn_mfma_f32_16x16x32_bf16(kf, qf[kk], s[st], 0, 0, 0);
      }
    }
    float ps = 0.0f;
    long long pu[4];
#pragma unroll
    for (int st = 0; st < 4; ++st) {
      PU t;
#pragma unroll
      for (int r = 0; r < 4; ++r) {
        float val = s[st][r];
        if (mask) {
          int kt = kt0 + st * 16 + quad * 4 + r;
          val = (kt <= q0 + l15) ? val : -3.0e38f;
        }
        float p = exp2f(val);
        ps += p;
        t.v[r] = (bf16_t)p;
      }
      pu[st] = t.u;
    }
    ps += __shfl_xor(ps, 16);
    ps += __shfl_xor(ps, 32);
    l_i += ps;
#pragma unroll
    for (int bb = 0; bb < 2; ++bb) {
      long long lo0 = __shfl(pu[2 * bb], lo);
      long long hi0 = __shfl(pu[2 * bb], lo + 16);
      long long lo1 = __shfl(pu[2 * bb + 1], lo);
      long long hi1 = __shfl(pu[2 * bb + 1], lo + 16);
      PF pf;
      pf.u[0] = (quad >= 2) ? lo1 : lo0;
      pf.u[1] = (quad >= 2) ? hi1 : hi0;
#pragma unroll
      for (int dt = 0; dt < 8; ++dt) {
        bf16x8 vf = *(const bf16x8*)&Vs[buf][dt * 16 + l15][(((bb * 4 + quad) ^ l15) & 7) * 8];
        oacc[dt] = __builtin_amdgcn_mfma_f32_16x16x32_bf16(pf.v, vf, oacc[dt], 0, 0, 0);
      }
    }
  };

  stage(0, 0);
  for (int ch = 0; ch < nchA; ++ch) {
    __syncthreads();
    if (ch + 1 < nchA) stage((ch + 1) & 1, (ch + 1) * 64);  // fly during compute
    const int kt0 = ch * 64;
    const int buf = ch & 1;
    step(buf, qfA, oaccA, l_A, q0A, kt0, ch == nchA - 1);
    if (ch < nchB) step(buf, qfB, oaccB, l_B, q0B, kt0, ch == nchB - 1);
  }

  float lrA[4], lrB[4];
#pragma unroll
  for (int r = 0; r < 4; ++r) {
    lrA[r] = __shfl(l_A, quad * 4 + r);
    lrB[r] = __shfl(l_B, quad * 4 + r);
  }
#pragma unroll
  for (int dt = 0; dt < 8; ++dt) {
#pragma unroll
    for (int r = 0; r < 4; ++r) {
      int d = dt * 16 + l15;
      int qa = q0A + quad * 4 + r;
      int qb = q0B + quad * 4 + r;
      O[((size_t)(b * T_ + qa)) * C_ + h * HD_ + d] = (bf16_t)(oaccA[dt][r] / lrA[r]);
      O[((size_t)(b * T_ + qb)) * C_ + h * HD_ + d] = (bf16_t)(oaccB[dt][r] / lrB[r]);
    }
  }
}

// ---------------- launch ----------------
extern "C" void kernel_launch(void* const* d_in, const int* in_sizes, int n_in,
                              void* d_out, int out_size, void* d_ws, size_t ws_size,
                              hipStream_t stream) {
  const float* x      = (const float*)d_in[0];
  const float* w_attn = (const float*)d_in[1];
  const float* b_attn = (const float*)d_in[2];
  const float* w_proj = (const float*)d_in[3];
  const float* b_proj = (const float*)d_in[4];
  float* out = (float*)d_out;

  char* p = (char*)d_ws;
  bf16_t* xb  = (bf16_t*)p; p += (size_t)4096 * 2048 * 2;      // x bf16 [B*T][C]
  bf16_t* waT = (bf16_t*)p; p += (size_t)6144 * 2048 * 2;      // w_attn^T bf16 [3C][C]
  bf16_t* wpT = (bf16_t*)p; p += (size_t)2048 * 2048 * 2;      // w_proj^T bf16 [C][C]
  bf16_t* Qb  = (bf16_t*)p; p += (size_t)32 * 2048 * 128 * 2;  // [B,H,T,hd] (pre-scaled)
  bf16_t* Kb  = (bf16_t*)p; p += (size_t)32 * 2048 * 128 * 2;  // [B,H,T,hd]
  bf16_t* Vb  = (bf16_t*)p; p += (size_t)32 * 2048 * 128 * 2;  // [B,H,hd,T] (transposed)
  bf16_t* Ob  = (bf16_t*)p; p += (size_t)4096 * 2048 * 2;      // attn out bf16 [B*T][C]

  cvt_f32_bf16<<<8192, 256, 0, stream>>>(x, xb, 2097152);
  transpose_cvt<<<dim3(6144 / 32, 2048 / 32), dim3(32, 8), 0, stream>>>(w_attn, waT, 2048, 6144);
  transpose_cvt<<<dim3(2048 / 32, 2048 / 32), dim3(32, 8), 0, stream>>>(w_proj, wpT, 2048, 2048);

  gemm_qkv<<<dim3(6144 / GBN, 4096 / GBM), 512, 0, stream>>>(
      xb, waT, b_attn, Qb, Kb, Vb, 2048);

  attn<<<dim3(16, 32), 256, 0, stream>>>(Qb, Kb, Vb, Ob);

  gemm_proj<<<dim3(2048 / TN, 4096 / TM), 256, 0, stream>>>(
      Ob, wpT, b_proj, out, 4096, 2048, 2048);
}

// Round 4
// 423.335 us; speedup vs baseline: 1.0261x; 1.0261x over previous
//
#include <hip/hip_runtime.h>
#include <cstdint>
#include <cstddef>

typedef __bf16 bf16_t;
typedef __bf16 bf16x8 __attribute__((ext_vector_type(8)));
typedef __bf16 bf16x4 __attribute__((ext_vector_type(4)));
typedef float floatx4 __attribute__((ext_vector_type(4)));

#define B_  2
#define T_  2048
#define C_  2048
#define H_  16
#define HD_ 128

// 1/sqrt(128) * log2(e) — folded into Q at QKV-GEMM epilogue
#define K_ATTN_SCALE (0.08838834764831843f * 1.44269504088896f)

// ---- async global->LDS, 16B per lane (m97 recipe) ----
__device__ __forceinline__ void async_copy16(const void* g, void* l) {
  __builtin_amdgcn_global_load_lds((const __attribute__((address_space(1))) unsigned int*)g,
                                   (__attribute__((address_space(3))) unsigned int*)l,
                                   16, 0, 0);
}

#define BAR()   asm volatile("s_barrier" ::: "memory")
#define LGKM0() do { asm volatile("s_waitcnt lgkmcnt(0)" ::: "memory"); \
                     __builtin_amdgcn_sched_barrier(0); } while (0)

// ---------------- convert fp32 -> bf16 (flat) ----------------
__global__ __launch_bounds__(256) void cvt_f32_bf16(const float* __restrict__ in,
                                                    bf16_t* __restrict__ out, int n4) {
  int i = blockIdx.x * 256 + threadIdx.x;
  if (i >= n4) return;
  const float4 v = ((const float4*)in)[i];
  bf16x4 o;
  o[0] = (bf16_t)v.x; o[1] = (bf16_t)v.y; o[2] = (bf16_t)v.z; o[3] = (bf16_t)v.w;
  ((bf16x4*)out)[i] = o;
}

// ------- transpose + convert: W[Kd][Nd] fp32 -> Wt[Nd][Kd] bf16 -------
__global__ __launch_bounds__(256) void transpose_cvt(const float* __restrict__ W,
                                                     bf16_t* __restrict__ Wt,
                                                     int Kd, int Nd) {
  __shared__ float tile[32][33];
  const int tx = threadIdx.x, ty = threadIdx.y;
  const int n0 = blockIdx.x * 32, k0 = blockIdx.y * 32;
#pragma unroll
  for (int j = ty; j < 32; j += 8)
    tile[j][tx] = W[(size_t)(k0 + j) * Nd + n0 + tx];
  __syncthreads();
#pragma unroll
  for (int j = ty; j < 32; j += 8)
    Wt[(size_t)(n0 + j) * Kd + k0 + tx] = (bf16_t)tile[tx][j];
}

// =====================================================================
// QKV GEMM — 256x256 tile, 8 waves, BK=64 staged as 2 k-slices of 32.
// LDS per buf: A [2 ks][256 r][64B] + B same = 64 KiB; 2 bufs = 128 KiB.
// 4 phases/tile (16 MFMA each, grouped by (mq,ks)); B-frags loaded once
// per ks -> 24 ds_read_b128/wave/tile.
// Pipeline: stage slice (t+1,k0) at P0(t), (t+1,k1) at P2(t).
// Counted waits BEFORE the guard barrier (cross-wave safe):
//   end-P1: vmcnt(4) drains (t,k1)   [last tile: vmcnt(0)]
//   end-P3: vmcnt(4) drains (t+1,k0) — never 0 in steady state.
// Swizzle for 64B rows: 16B slot ^= (r>>1)&3  (bank-quad = 4*(r&1) + slot
// -> 8 distinct quads over 8 lanes, 2-way residual = free).
// =====================================================================
#define GBM 256
#define GBN 256
#define GBK 64

__global__ __launch_bounds__(512, 2) void gemm_qkv(
    const bf16_t* __restrict__ A, const bf16_t* __restrict__ Bt,
    const float* __restrict__ bias,
    bf16_t* __restrict__ Qo, bf16_t* __restrict__ Ko, bf16_t* __restrict__ Vo,
    int K) {
  __shared__ __align__(16) char smem[131072];
  const int tid = threadIdx.x;
  const int wave = tid >> 6, lane = tid & 63;
  const int quad = lane >> 4, l15 = lane & 15;
  const int wm = wave >> 2, wn = wave & 3;
  const int bm = blockIdx.y * GBM, bn = blockIdx.x * GBN;

  // ---- staging map: linear LDS dest <- inverse-swizzled global source ----
  // per 16KB slice: p = l*8192 + tid*16; row r = p>>6; phys slot (p>>4)&3
  // holds logical slot ((p>>4)&3) ^ ((r>>1)&3).
  const bf16_t* asrc[2];
  const bf16_t* bsrc[2];
#pragma unroll
  for (int l = 0; l < 2; ++l) {
    int p = l * 8192 + tid * 16;
    int r = p >> 6;
    int c = ((p >> 4) & 3) ^ ((r >> 1) & 3);
    asrc[l] = A  + (size_t)(bm + r) * K + c * 8;
    bsrc[l] = Bt + (size_t)(bn + r) * K + c * 8;
  }

  // stage one k-slice (A+B, 4 loads/thread) of tile with k-offset kofs
  auto stage = [&](int buf, int ks, int kofs) {
    char* Asl = smem + buf * 65536 + ks * 16384;
    char* Bsl = Asl + 32768;
#pragma unroll
    for (int l = 0; l < 2; ++l)
      async_copy16(asrc[l] + kofs, Asl + l * 8192 + tid * 16);
#pragma unroll
    for (int l = 0; l < 2; ++l)
      async_copy16(bsrc[l] + kofs, Bsl + l * 8192 + tid * 16);
  };

  // ---- read-side: within-slice byte = row*64 + ((quad*16) ^ sxr) ----
  const int sxr = ((l15 >> 1) & 3) << 4;     // (r>>1)&3 == (l15>>1)&3 for 16-step rows
  const int cb  = (quad * 16) ^ sxr;
  const int arow = (wm * 128 + l15) * 64;    // + mq*4096 + i*1024
  const int brow = (wn * 64 + l15) * 64;     // + j*1024

  floatx4 acc[8][4] = {};
  bf16x8 af[4], bfr[4];

  // ---- prologue: stage both slices of tile 0 ----
  stage(0, 0, 0);
  stage(0, 1, 32);
  asm volatile("s_waitcnt vmcnt(4)" ::: "memory");   // slice (0,k0) complete
  BAR();

  const int NT = K / GBK;   // 32
  for (int t = 0; t < NT; ++t) {
    const int buf = t & 1;
    const char* Ab = smem + buf * 65536;
    const char* Bb = Ab + 32768;
    const bool st = (t + 1 < NT);
    const int nk = (t + 1) * GBK;

    // -------- P0: ks=0, mq=0 --------
#pragma unroll
    for (int j = 0; j < 4; ++j)
      bfr[j] = *(const bf16x8*)(Bb + brow + j * 1024 + cb);
#pragma unroll
    for (int i = 0; i < 4; ++i)
      af[i] = *(const bf16x8*)(Ab + arow + i * 1024 + cb);
    if (st) stage(buf ^ 1, 0, nk);
    BAR();
    LGKM0();
    __builtin_amdgcn_s_setprio(1);
#pragma unroll
    for (int i = 0; i < 4; ++i)
#pragma unroll
      for (int j = 0; j < 4; ++j)
        acc[i][j] = __builtin_amdgcn_mfma_f32_16x16x32_bf16(af[i], bfr[j], acc[i][j], 0, 0, 0);
    __builtin_amdgcn_s_setprio(0);
    BAR();

    // -------- P1: ks=0, mq=1 --------
#pragma unroll
    for (int i = 0; i < 4; ++i)
      af[i] = *(const bf16x8*)(Ab + arow + 4096 + i * 1024 + cb);
    BAR();
    LGKM0();
    __builtin_amdgcn_s_setprio(1);
#pragma unroll
    for (int i = 0; i < 4; ++i)
#pragma unroll
      for (int j = 0; j < 4; ++j)
        acc[4 + i][j] = __builtin_amdgcn_mfma_f32_16x16x32_bf16(af[i], bfr[j], acc[4 + i][j], 0, 0, 0);
    __builtin_amdgcn_s_setprio(0);
    if (t == NT - 1) {
      asm volatile("s_waitcnt vmcnt(0)" ::: "memory");   // drain (t,k1): nothing younger
    } else {
      asm volatile("s_waitcnt vmcnt(4)" ::: "memory");   // drain (t,k1); (t+1,k0) flies
    }
    BAR();

    // -------- P2: ks=1, mq=0 --------
#pragma unroll
    for (int j = 0; j < 4; ++j)
      bfr[j] = *(const bf16x8*)(Bb + 16384 + brow + j * 1024 + cb);
#pragma unroll
    for (int i = 0; i < 4; ++i)
      af[i] = *(const bf16x8*)(Ab + 16384 + arow + i * 1024 + cb);
    if (st) stage(buf ^ 1, 1, nk + 32);
    BAR();
    LGKM0();
    __builtin_amdgcn_s_setprio(1);
#pragma unroll
    for (int i = 0; i < 4; ++i)
#pragma unroll
      for (int j = 0; j < 4; ++j)
        acc[i][j] = __builtin_amdgcn_mfma_f32_16x16x32_bf16(af[i], bfr[j], acc[i][j], 0, 0, 0);
    __builtin_amdgcn_s_setprio(0);
    BAR();

    // -------- P3: ks=1, mq=1 --------
#pragma unroll
    for (int i = 0; i < 4; ++i)
      af[i] = *(const bf16x8*)(Ab + 16384 + arow + 4096 + i * 1024 + cb);
    BAR();
    LGKM0();
    __builtin_amdgcn_s_setprio(1);
#pragma unroll
    for (int i = 0; i < 4; ++i)
#pragma unroll
      for (int j = 0; j < 4; ++j)
        acc[4 + i][j] = __builtin_amdgcn_mfma_f32_16x16x32_bf16(af[i], bfr[j], acc[4 + i][j], 0, 0, 0);
    __builtin_amdgcn_s_setprio(0);
    if (t < NT - 1)
      asm volatile("s_waitcnt vmcnt(4)" ::: "memory");   // drain (t+1,k0); (t+1,k1) flies
    BAR();
  }

  // ---------------- epilogue ----------------
  float bias_r[4];
#pragma unroll
  for (int j = 0; j < 4; ++j)
    bias_r[j] = bias[bn + wn * 64 + j * 16 + l15];

  if (bn < 2 * C_) {
    // ---- Q / K scatter to [B,H,T,hd] ----
    const int which = bn >> 11;  // 0 = Q, 1 = K (uniform per block)
    bf16_t* dst0 = which ? Ko : Qo;
    const float scl = which ? 1.0f : K_ATTN_SCALE;
#pragma unroll
    for (int i = 0; i < 8; ++i) {
      const int m = bm + wm * 128 + i * 16 + quad * 4;
      const int b = m >> 11, tq = m & 2047;
#pragma unroll
      for (int j = 0; j < 4; ++j) {
        const int n = bn + wn * 64 + j * 16 + l15;
        const int cc = n & 2047;
        const int h = cc >> 7, d = cc & 127;
        bf16_t* dst = dst0 + (((size_t)(b * H_ + h)) * T_ + tq) * HD_ + d;
#pragma unroll
        for (int r = 0; r < 4; ++r)
          dst[(size_t)r * HD_] = (bf16_t)((acc[i][j][r] + bias_r[j]) * scl);
      }
    }
  } else {
    // ---- V block: transpose 256x256 tile through LDS (full 128 KiB) ----
    __syncthreads();  // all waves fully past main-loop LDS reads
    bf16_t* vt = (bf16_t*)smem;
#pragma unroll
    for (int i = 0; i < 8; ++i) {
      const int tl = wm * 128 + i * 16 + quad * 4;
#pragma unroll
      for (int j = 0; j < 4; ++j) {
        const int dl = wn * 64 + j * 16 + l15;
        const int sw = 8 * (dl & 15);
#pragma unroll
        for (int r = 0; r < 4; ++r)
          vt[dl * 256 + ((tl + r) ^ sw)] = (bf16_t)(acc[i][j][r] + bias_r[j]);
      }
    }
    __syncthreads();
    const int dr = tid >> 1, half = tid & 1;
    const int h = ((bn - 2 * C_) >> 7) + (dr >> 7);
    const int b = bm >> 11, t0g = bm & 2047;
    bf16_t* dst = Vo + ((size_t)(b * H_ + h) * HD_ + (dr & 127)) * T_ + t0g;
#pragma unroll
    for (int cc2 = 0; cc2 < 16; ++cc2) {
      const int c = half * 16 + cc2;
      uint4 v = *(const uint4*)&vt[dr * 256 + ((c ^ (dr & 15)) * 8)];
      *(uint4*)(dst + c * 8) = v;
    }
  }
}

// ---------------- proj GEMM (m97 structure + XOR-swizzled LDS, fp32 out) ----------------
#define TM 128
#define TN 128
#define BK 64

__global__ __launch_bounds__(256) void gemm_proj(
    const bf16_t* __restrict__ A, const bf16_t* __restrict__ Bt,
    const float* __restrict__ bias, float* __restrict__ Cout,
    int M, int N, int K) {
  __shared__ __align__(16) char smem[32768];
  bf16_t (*As)[BK] = (bf16_t(*)[BK])smem;              // 16 KB
  bf16_t (*Bs)[BK] = (bf16_t(*)[BK])(smem + 16384);    // 16 KB
  const int tid = threadIdx.x;
  const int wave = tid >> 6, lane = tid & 63;
  const int quad = lane >> 4, l15 = lane & 15;
  const int bm = blockIdx.y * TM, bn = blockIdx.x * TN;
  const int wm = (wave >> 1) * 64, wn = (wave & 1) * 64;
  const int sw = l15 & 7;   // read-side swizzle

  floatx4 acc[4][4] = {};

  for (int k0 = 0; k0 < K; k0 += BK) {
#pragma unroll
    for (int it = 0; it < 4; ++it) {
      int p = it * 4096 + tid * 16;      // LDS byte offset (lane-linear)
      int r = p >> 7;                    // tile row
      int cg = ((p >> 4) & 7) ^ (r & 7); // global chunk held by this slot
      async_copy16(A + (size_t)(bm + r) * K + k0 + cg * 8, (char*)&As[0][0] + p);
      async_copy16(Bt + (size_t)(bn + r) * K + k0 + cg * 8, (char*)&Bs[0][0] + p);
    }
    __syncthreads();
#pragma unroll
    for (int kc = 0; kc < 2; ++kc) {
      const int cidx = (kc * 4 + quad) ^ sw;
      bf16x8 af[4], bf[4];
#pragma unroll
      for (int i = 0; i < 4; ++i)
        af[i] = *(const bf16x8*)&As[wm + i * 16 + l15][cidx * 8];
#pragma unroll
      for (int j = 0; j < 4; ++j)
        bf[j] = *(const bf16x8*)&Bs[wn + j * 16 + l15][cidx * 8];
#pragma unroll
      for (int i = 0; i < 4; ++i)
#pragma unroll
        for (int j = 0; j < 4; ++j)
          acc[i][j] = __builtin_amdgcn_mfma_f32_16x16x32_bf16(af[i], bf[j], acc[i][j], 0, 0, 0);
    }
    __syncthreads();
  }

#pragma unroll
  for (int i = 0; i < 4; ++i) {
#pragma unroll
    for (int j = 0; j < 4; ++j) {
#pragma unroll
      for (int r = 0; r < 4; ++r) {
        int m = bm + wm + i * 16 + quad * 4 + r;
        int n = bn + wn + j * 16 + l15;
        Cout[(size_t)m * N + n] = acc[i][j][r] + bias[n];
      }
    }
  }
}

// ---------------- causal flash attention (double-buffered K/V staging) ----------------
__global__ __launch_bounds__(256) void attn(const bf16_t* __restrict__ Q,
                                            const bf16_t* __restrict__ Kg,
                                            const bf16_t* __restrict__ Vt,
                                            bf16_t* __restrict__ O) {
  __shared__ bf16_t Ks[2][64][128];   // rows 256B=16 chunks; chunk c of row r at c^(r&15)
  __shared__ bf16_t Vs[2][128][64];   // rows 128B=8 chunks;  chunk c of row r at c^(r&7)
  const int tid = threadIdx.x;
  const int wave = tid >> 6, lane = tid & 63;
  const int quad = lane >> 4, l15 = lane & 15;
  const int j = blockIdx.x;        // 0..15
  const int bh = blockIdx.y;
  const int b = bh >> 4, h = bh & 15;
  const int qtA = 31 - j, qtB = j;           // heavy, light
  const int nchA = qtA + 1, nchB = qtB + 1;
  const int q0A = qtA * 64 + wave * 16;
  const int q0B = qtB * 64 + wave * 16;

  const bf16_t* Qh = Q + (size_t)bh * T_ * HD_;
  const bf16_t* Kh = Kg + (size_t)bh * T_ * HD_;
  const bf16_t* Vh = Vt + (size_t)bh * HD_ * T_;

  bf16x8 qfA[4], qfB[4];
#pragma unroll
  for (int kk = 0; kk < 4; ++kk) {
    qfA[kk] = *(const bf16x8*)(Qh + (size_t)(q0A + l15) * HD_ + kk * 32 + quad * 8);
    qfB[kk] = *(const bf16x8*)(Qh + (size_t)(q0B + l15) * HD_ + kk * 32 + quad * 8);
  }

  floatx4 oaccA[8] = {}, oaccB[8] = {};
  float l_A = 0.0f, l_B = 0.0f;

  union PU { bf16x4 v; long long u; };
  union PF { long long u[2]; bf16x8 v; };
  const int lo = ((lane & 16) << 1) + l15;  // (quad&1)*32 + l15

  auto stage = [&](int buf, int kt0) {
#pragma unroll
    for (int it = 0; it < 4; ++it) {
      int p = it * 4096 + tid * 16;
      int r = p >> 8;
      int cg = ((p >> 4) & 15) ^ (r & 15);
      async_copy16(Kh + (size_t)(kt0 + r) * HD_ + cg * 8, (char*)&Ks[buf][0][0] + p);
    }
#pragma unroll
    for (int it = 0; it < 4; ++it) {
      int p = it * 4096 + tid * 16;
      int r = p >> 7;
      int cg = ((p >> 4) & 7) ^ (r & 7);
      async_copy16(Vh + (size_t)r * T_ + kt0 + cg * 8, (char*)&Vs[buf][0][0] + p);
    }
  };

  auto step = [&](int buf, const bf16x8* qf, floatx4* oacc, float& l_i, int q0, int kt0,
                  bool mask) {
    floatx4 s[4] = {{}, {}, {}, {}};
#pragma unroll
    for (int st = 0; st < 4; ++st) {
#pragma unroll
      for (int kk = 0; kk < 4; ++kk) {
        bf16x8 kf = *(const bf16x8*)&Ks[buf][st * 16 + l15][(((kk * 4 + quad) ^ l15) & 15) * 8];
        s[st] = __builtin_amdgcn_mfma_f32_16x16x32_bf16(kf, qf[kk], s[st], 0, 0, 0);
      }
    }
    float ps = 0.0f;
    long long pu[4];
#pragma unroll
    for (int st = 0; st < 4; ++st) {
      PU t;
#pragma unroll
      for (int r = 0; r < 4; ++r) {
        float val = s[st][r];
        if (mask) {
          int kt = kt0 + st * 16 + quad * 4 + r;
          val = (kt <= q0 + l15) ? val : -3.0e38f;
        }
        float p = exp2f(val);
        ps += p;
        t.v[r] = (bf16_t)p;
      }
      pu[st] = t.u;
    }
    ps += __shfl_xor(ps, 16);
    ps += __shfl_xor(ps, 32);
    l_i += ps;
#pragma unroll
    for (int bb = 0; bb < 2; ++bb) {
      long long lo0 = __shfl(pu[2 * bb], lo);
      long long hi0 = __shfl(pu[2 * bb], lo + 16);
      long long lo1 = __shfl(pu[2 * bb + 1], lo);
      long long hi1 = __shfl(pu[2 * bb + 1], lo + 16);
      PF pf;
      pf.u[0] = (quad >= 2) ? lo1 : lo0;
      pf.u[1] = (quad >= 2) ? hi1 : hi0;
#pragma unroll
      for (int dt = 0; dt < 8; ++dt) {
        bf16x8 vf = *(const bf16x8*)&Vs[buf][dt * 16 + l15][(((bb * 4 + quad) ^ l15) & 7) * 8];
        oacc[dt] = __builtin_amdgcn_mfma_f32_16x16x32_bf16(pf.v, vf, oacc[dt], 0, 0, 0);
      }
    }
  };

  stage(0, 0);
  for (int ch = 0; ch < nchA; ++ch) {
    __syncthreads();
    if (ch + 1 < nchA) stage((ch + 1) & 1, (ch + 1) * 64);  // fly during compute
    const int kt0 = ch * 64;
    const int buf = ch & 1;
    step(buf, qfA, oaccA, l_A, q0A, kt0, ch == nchA - 1);
    if (ch < nchB) step(buf, qfB, oaccB, l_B, q0B, kt0, ch == nchB - 1);
  }

  float lrA[4], lrB[4];
#pragma unroll
  for (int r = 0; r < 4; ++r) {
    lrA[r] = __shfl(l_A, quad * 4 + r);
    lrB[r] = __shfl(l_B, quad * 4 + r);
  }
#pragma unroll
  for (int dt = 0; dt < 8; ++dt) {
#pragma unroll
    for (int r = 0; r < 4; ++r) {
      int d = dt * 16 + l15;
      int qa = q0A + quad * 4 + r;
      int qb = q0B + quad * 4 + r;
      O[((size_t)(b * T_ + qa)) * C_ + h * HD_ + d] = (bf16_t)(oaccA[dt][r] / lrA[r]);
      O[((size_t)(b * T_ + qb)) * C_ + h * HD_ + d] = (bf16_t)(oaccB[dt][r] / lrB[r]);
    }
  }
}

// ---------------- launch ----------------
extern "C" void kernel_launch(void* const* d_in, const int* in_sizes, int n_in,
                              void* d_out, int out_size, void* d_ws, size_t ws_size,
                              hipStream_t stream) {
  const float* x      = (const float*)d_in[0];
  const float* w_attn = (const float*)d_in[1];
  const float* b_attn = (const float*)d_in[2];
  const float* w_proj = (const float*)d_in[3];
  const float* b_proj = (const float*)d_in[4];
  float* out = (float*)d_out;

  char* p = (char*)d_ws;
  bf16_t* xb  = (bf16_t*)p; p += (size_t)4096 * 2048 * 2;      // x bf16 [B*T][C]
  bf16_t* waT = (bf16_t*)p; p += (size_t)6144 * 2048 * 2;      // w_attn^T bf16 [3C][C]
  bf16_t* wpT = (bf16_t*)p; p += (size_t)2048 * 2048 * 2;      // w_proj^T bf16 [C][C]
  bf16_t* Qb  = (bf16_t*)p; p += (size_t)32 * 2048 * 128 * 2;  // [B,H,T,hd] (pre-scaled)
  bf16_t* Kb  = (bf16_t*)p; p += (size_t)32 * 2048 * 128 * 2;  // [B,H,T,hd]
  bf16_t* Vb  = (bf16_t*)p; p += (size_t)32 * 2048 * 128 * 2;  // [B,H,hd,T] (transposed)
  bf16_t* Ob  = (bf16_t*)p; p += (size_t)4096 * 2048 * 2;      // attn out bf16 [B*T][C]

  cvt_f32_bf16<<<8192, 256, 0, stream>>>(x, xb, 2097152);
  transpose_cvt<<<dim3(6144 / 32, 2048 / 32), dim3(32, 8), 0, stream>>>(w_attn, waT, 2048, 6144);
  transpose_cvt<<<dim3(2048 / 32, 2048 / 32), dim3(32, 8), 0, stream>>>(w_proj, wpT, 2048, 2048);

  gemm_qkv<<<dim3(6144 / GBN, 4096 / GBM), 512, 0, stream>>>(
      xb, waT, b_attn, Qb, Kb, Vb, 2048);

  attn<<<dim3(16, 32), 256, 0, stream>>>(Qb, Kb, Vb, Ob);

  gemm_proj<<<dim3(2048 / TN, 4096 / TM), 256, 0, stream>>>(
      Ob, wpT, b_proj, out, 4096, 2048, 2048);
}

// Round 5
// 410.558 us; speedup vs baseline: 1.0580x; 1.0311x over previous
//
#include <hip/hip_runtime.h>
#include <cstdint>
#include <cstddef>

typedef __bf16 bf16_t;
typedef __bf16 bf16x8 __attribute__((ext_vector_type(8)));
typedef __bf16 bf16x4 __attribute__((ext_vector_type(4)));
typedef float floatx4 __attribute__((ext_vector_type(4)));

#define B_  2
#define T_  2048
#define C_  2048
#define H_  16
#define HD_ 128

// 1/sqrt(128) * log2(e) — folded into Q at QKV-GEMM epilogue
#define K_ATTN_SCALE (0.08838834764831843f * 1.44269504088896f)

// ---- async global->LDS, 16B per lane (m97 recipe) ----
__device__ __forceinline__ void async_copy16(const void* g, void* l) {
  __builtin_amdgcn_global_load_lds((const __attribute__((address_space(1))) unsigned int*)g,
                                   (__attribute__((address_space(3))) unsigned int*)l,
                                   16, 0, 0);
}

#define BAR()     asm volatile("s_barrier" ::: "memory")
#define VMCNT(n)  asm volatile("s_waitcnt vmcnt(" #n ")" ::: "memory")

// ---------------- convert fp32 -> bf16 (flat) ----------------
__global__ __launch_bounds__(256) void cvt_f32_bf16(const float* __restrict__ in,
                                                    bf16_t* __restrict__ out, int n4) {
  int i = blockIdx.x * 256 + threadIdx.x;
  if (i >= n4) return;
  const float4 v = ((const float4*)in)[i];
  bf16x4 o;
  o[0] = (bf16_t)v.x; o[1] = (bf16_t)v.y; o[2] = (bf16_t)v.z; o[3] = (bf16_t)v.w;
  ((bf16x4*)out)[i] = o;
}

// ------- transpose + convert: W[Kd][Nd] fp32 -> Wt[Nd][Kd] bf16 -------
__global__ __launch_bounds__(256) void transpose_cvt(const float* __restrict__ W,
                                                     bf16_t* __restrict__ Wt,
                                                     int Kd, int Nd) {
  __shared__ float tile[32][33];
  const int tx = threadIdx.x, ty = threadIdx.y;
  const int n0 = blockIdx.x * 32, k0 = blockIdx.y * 32;
#pragma unroll
  for (int j = ty; j < 32; j += 8)
    tile[j][tx] = W[(size_t)(k0 + j) * Nd + n0 + tx];
  __syncthreads();
#pragma unroll
  for (int j = ty; j < 32; j += 8)
    Wt[(size_t)(n0 + j) * Kd + k0 + tx] = (bf16_t)tile[tx][j];
}

// =====================================================================
// QKV GEMM — 256x256 tile, 8 waves, BK=64 as 2 k-slices of 32.
// Register FRAGMENT double-buffer: each phase's ds_reads are issued during
// the PREVIOUS phase's MFMA cluster (compiler-visible loads, no fences ->
// scheduler interleaves reads among MFMAs; lgkm waits auto-inserted).
// 2 barriers/tile (end-P0, end-P2), each preceded by counted vmcnt(8):
// 12 loads in flight, drain oldest 4; each slice gets ~4 phases of flight.
// Staging: P0(t) stages (t+1,k1); P2(t) stages (t+2,k0).
// Swizzle (64B rows): 16B slot ^= (r>>1)&3 (bank-quad = 4*(r&1)+slot).
// =====================================================================
#define GBM 256
#define GBN 256
#define GBK 64

__global__ __launch_bounds__(512, 2) void gemm_qkv(
    const bf16_t* __restrict__ A, const bf16_t* __restrict__ Bt,
    const float* __restrict__ bias,
    bf16_t* __restrict__ Qo, bf16_t* __restrict__ Ko, bf16_t* __restrict__ Vo,
    int K) {
  __shared__ __align__(16) char smem[131072];
  const int tid = threadIdx.x;
  const int wave = tid >> 6, lane = tid & 63;
  const int quad = lane >> 4, l15 = lane & 15;
  const int wm = wave >> 2, wn = wave & 3;
  const int bm = blockIdx.y * GBM, bn = blockIdx.x * GBN;

  // ---- staging map: linear LDS dest <- inverse-swizzled global source ----
  const bf16_t* asrc[2];
  const bf16_t* bsrc[2];
#pragma unroll
  for (int l = 0; l < 2; ++l) {
    int p = l * 8192 + tid * 16;
    int r = p >> 6;
    int c = ((p >> 4) & 3) ^ ((r >> 1) & 3);
    asrc[l] = A  + (size_t)(bm + r) * K + c * 8;
    bsrc[l] = Bt + (size_t)(bn + r) * K + c * 8;
  }

  // stage one k-slice (A+B, 4 loads/thread) of tile with k-offset kofs
  auto stage = [&](int buf, int ks, int kofs) {
    char* Asl = smem + buf * 65536 + ks * 16384;
    char* Bsl = Asl + 32768;
#pragma unroll
    for (int l = 0; l < 2; ++l)
      async_copy16(asrc[l] + kofs, Asl + l * 8192 + tid * 16);
#pragma unroll
    for (int l = 0; l < 2; ++l)
      async_copy16(bsrc[l] + kofs, Bsl + l * 8192 + tid * 16);
  };

  // ---- read-side addressing ----
  const int sxr = ((l15 >> 1) & 3) << 4;     // (r>>1)&3 == (l15>>1)&3
  const int cb  = (quad * 16) ^ sxr;
  const int arow = (wm * 128 + l15) * 64;    // + mq*4096 + i*1024
  const int brow = (wn * 64 + l15) * 64;     // + j*1024

  floatx4 acc[8][4] = {};
  bf16x8 a0[4], a1[4], b0[4], b1[4];

  // ---- prologue: (0,k0), (0,k1), (1,k0) in flight; drain (0,k0); read P0 frags ----
  stage(0, 0, 0);
  stage(0, 1, 32);
  stage(1, 0, GBK);
  VMCNT(8);
  BAR();
  {
    const char* Ab = smem;
    const char* Bb = smem + 32768;
#pragma unroll
    for (int i = 0; i < 4; ++i)
      a0[i] = *(const bf16x8*)(Ab + arow + i * 1024 + cb);
#pragma unroll
    for (int j = 0; j < 4; ++j)
      b0[j] = *(const bf16x8*)(Bb + brow + j * 1024 + cb);
  }

  const int NT = K / GBK;   // 32
  for (int t = 0; t < NT; ++t) {
    const char* Ab  = smem + (t & 1) * 65536;
    const char* Bb  = Ab + 32768;
    const char* Abn = smem + ((t + 1) & 1) * 65536;
    const char* Bbn = Abn + 32768;

    // -------- P0: MFMA(a0,b0)->acc[0..3]; load a1=(ks0,mq1); stage (t+1,k1) --------
#pragma unroll
    for (int i = 0; i < 4; ++i)
      a1[i] = *(const bf16x8*)(Ab + arow + 4096 + i * 1024 + cb);
    if (t + 1 < NT) stage((t + 1) & 1, 1, (t + 1) * GBK + 32);
#pragma unroll
    for (int i = 0; i < 4; ++i)
#pragma unroll
      for (int j = 0; j < 4; ++j)
        acc[i][j] = __builtin_amdgcn_mfma_f32_16x16x32_bf16(a0[i], b0[j], acc[i][j], 0, 0, 0);
    if (t + 1 < NT) { VMCNT(8); } else { VMCNT(0); }   // drain (t,k1)
    BAR();

    // -------- P1: MFMA(a1,b0)->acc[4..7]; load a0=(ks1,mq0), b1=(ks1) --------
#pragma unroll
    for (int i = 0; i < 4; ++i)
      a0[i] = *(const bf16x8*)(Ab + 16384 + arow + i * 1024 + cb);
#pragma unroll
    for (int j = 0; j < 4; ++j)
      b1[j] = *(const bf16x8*)(Bb + 16384 + brow + j * 1024 + cb);
#pragma unroll
    for (int i = 0; i < 4; ++i)
#pragma unroll
      for (int j = 0; j < 4; ++j)
        acc[4 + i][j] = __builtin_amdgcn_mfma_f32_16x16x32_bf16(a1[i], b0[j], acc[4 + i][j], 0, 0, 0);
    // no barrier

    // -------- P2: MFMA(a0,b1)->acc[0..3]; load a1=(ks1,mq1); stage (t+2,k0) --------
#pragma unroll
    for (int i = 0; i < 4; ++i)
      a1[i] = *(const bf16x8*)(Ab + 16384 + arow + 4096 + i * 1024 + cb);
    if (t + 2 < NT) stage(t & 1, 0, (t + 2) * GBK);
#pragma unroll
    for (int i = 0; i < 4; ++i)
#pragma unroll
      for (int j = 0; j < 4; ++j)
        acc[i][j] = __builtin_amdgcn_mfma_f32_16x16x32_bf16(a0[i], b1[j], acc[i][j], 0, 0, 0);
    if (t + 2 < NT)      { VMCNT(8); }                 // drain (t+1,k0)
    else if (t + 1 < NT) { VMCNT(4); }
    else                 { VMCNT(0); }
    BAR();

    // -------- P3: MFMA(a1,b1)->acc[4..7]; load a0,b0 = next tile (ks0,mq0) --------
    if (t + 1 < NT) {
#pragma unroll
      for (int i = 0; i < 4; ++i)
        a0[i] = *(const bf16x8*)(Abn + arow + i * 1024 + cb);
#pragma unroll
      for (int j = 0; j < 4; ++j)
        b0[j] = *(const bf16x8*)(Bbn + brow + j * 1024 + cb);
    }
#pragma unroll
    for (int i = 0; i < 4; ++i)
#pragma unroll
      for (int j = 0; j < 4; ++j)
        acc[4 + i][j] = __builtin_amdgcn_mfma_f32_16x16x32_bf16(a1[i], b1[j], acc[4 + i][j], 0, 0, 0);
    // no barrier
  }

  // ---------------- epilogue ----------------
  float bias_r[4];
#pragma unroll
  for (int j = 0; j < 4; ++j)
    bias_r[j] = bias[bn + wn * 64 + j * 16 + l15];

  if (bn < 2 * C_) {
    // ---- Q / K scatter to [B,H,T,hd] ----
    const int which = bn >> 11;  // 0 = Q, 1 = K (uniform per block)
    bf16_t* dst0 = which ? Ko : Qo;
    const float scl = which ? 1.0f : K_ATTN_SCALE;
#pragma unroll
    for (int i = 0; i < 8; ++i) {
      const int m = bm + wm * 128 + i * 16 + quad * 4;
      const int b = m >> 11, tq = m & 2047;
#pragma unroll
      for (int j = 0; j < 4; ++j) {
        const int n = bn + wn * 64 + j * 16 + l15;
        const int cc = n & 2047;
        const int h = cc >> 7, d = cc & 127;
        bf16_t* dst = dst0 + (((size_t)(b * H_ + h)) * T_ + tq) * HD_ + d;
#pragma unroll
        for (int r = 0; r < 4; ++r)
          dst[(size_t)r * HD_] = (bf16_t)((acc[i][j][r] + bias_r[j]) * scl);
      }
    }
  } else {
    // ---- V block: transpose 256x256 tile through LDS (full 128 KiB) ----
    __syncthreads();  // all waves fully past main-loop LDS reads
    bf16_t* vt = (bf16_t*)smem;
#pragma unroll
    for (int i = 0; i < 8; ++i) {
      const int tl = wm * 128 + i * 16 + quad * 4;
#pragma unroll
      for (int j = 0; j < 4; ++j) {
        const int dl = wn * 64 + j * 16 + l15;
        const int sw = 8 * (dl & 15);
#pragma unroll
        for (int r = 0; r < 4; ++r)
          vt[dl * 256 + ((tl + r) ^ sw)] = (bf16_t)(acc[i][j][r] + bias_r[j]);
      }
    }
    __syncthreads();
    const int dr = tid >> 1, half = tid & 1;
    const int h = ((bn - 2 * C_) >> 7) + (dr >> 7);
    const int b = bm >> 11, t0g = bm & 2047;
    bf16_t* dst = Vo + ((size_t)(b * H_ + h) * HD_ + (dr & 127)) * T_ + t0g;
#pragma unroll
    for (int cc2 = 0; cc2 < 16; ++cc2) {
      const int c = half * 16 + cc2;
      uint4 v = *(const uint4*)&vt[dr * 256 + ((c ^ (dr & 15)) * 8)];
      *(uint4*)(dst + c * 8) = v;
    }
  }
}

// ---------------- proj GEMM (m97 structure + XOR-swizzled LDS, fp32 out) ----------------
#define TM 128
#define TN 128
#define BK 64

__global__ __launch_bounds__(256) void gemm_proj(
    const bf16_t* __restrict__ A, const bf16_t* __restrict__ Bt,
    const float* __restrict__ bias, float* __restrict__ Cout,
    int M, int N, int K) {
  __shared__ __align__(16) char smem[32768];
  bf16_t (*As)[BK] = (bf16_t(*)[BK])smem;              // 16 KB
  bf16_t (*Bs)[BK] = (bf16_t(*)[BK])(smem + 16384);    // 16 KB
  const int tid = threadIdx.x;
  const int wave = tid >> 6, lane = tid & 63;
  const int quad = lane >> 4, l15 = lane & 15;
  const int bm = blockIdx.y * TM, bn = blockIdx.x * TN;
  const int wm = (wave >> 1) * 64, wn = (wave & 1) * 64;
  const int sw = l15 & 7;   // read-side swizzle

  floatx4 acc[4][4] = {};

  for (int k0 = 0; k0 < K; k0 += BK) {
#pragma unroll
    for (int it = 0; it < 4; ++it) {
      int p = it * 4096 + tid * 16;      // LDS byte offset (lane-linear)
      int r = p >> 7;                    // tile row
      int cg = ((p >> 4) & 7) ^ (r & 7); // global chunk held by this slot
      async_copy16(A + (size_t)(bm + r) * K + k0 + cg * 8, (char*)&As[0][0] + p);
      async_copy16(Bt + (size_t)(bn + r) * K + k0 + cg * 8, (char*)&Bs[0][0] + p);
    }
    __syncthreads();
#pragma unroll
    for (int kc = 0; kc < 2; ++kc) {
      const int cidx = (kc * 4 + quad) ^ sw;
      bf16x8 af[4], bf[4];
#pragma unroll
      for (int i = 0; i < 4; ++i)
        af[i] = *(const bf16x8*)&As[wm + i * 16 + l15][cidx * 8];
#pragma unroll
      for (int j = 0; j < 4; ++j)
        bf[j] = *(const bf16x8*)&Bs[wn + j * 16 + l15][cidx * 8];
#pragma unroll
      for (int i = 0; i < 4; ++i)
#pragma unroll
        for (int j = 0; j < 4; ++j)
          acc[i][j] = __builtin_amdgcn_mfma_f32_16x16x32_bf16(af[i], bf[j], acc[i][j], 0, 0, 0);
    }
    __syncthreads();
  }

#pragma unroll
  for (int i = 0; i < 4; ++i) {
#pragma unroll
    for (int j = 0; j < 4; ++j) {
#pragma unroll
      for (int r = 0; r < 4; ++r) {
        int m = bm + wm + i * 16 + quad * 4 + r;
        int n = bn + wn + j * 16 + l15;
        Cout[(size_t)m * N + n] = acc[i][j][r] + bias[n];
      }
    }
  }
}

// ---------------- causal flash attention (double-buffered K/V staging) ----------------
__global__ __launch_bounds__(256) void attn(const bf16_t* __restrict__ Q,
                                            const bf16_t* __restrict__ Kg,
                                            const bf16_t* __restrict__ Vt,
                                            bf16_t* __restrict__ O) {
  __shared__ bf16_t Ks[2][64][128];   // rows 256B=16 chunks; chunk c of row r at c^(r&15)
  __shared__ bf16_t Vs[2][128][64];   // rows 128B=8 chunks;  chunk c of row r at c^(r&7)
  const int tid = threadIdx.x;
  const int wave = tid >> 6, lane = tid & 63;
  const int quad = lane >> 4, l15 = lane & 15;
  const int j = blockIdx.x;        // 0..15
  const int bh = blockIdx.y;
  const int b = bh >> 4, h = bh & 15;
  const int qtA = 31 - j, qtB = j;           // heavy, light
  const int nchA = qtA + 1, nchB = qtB + 1;
  const int q0A = qtA * 64 + wave * 16;
  const int q0B = qtB * 64 + wave * 16;

  const bf16_t* Qh = Q + (size_t)bh * T_ * HD_;
  const bf16_t* Kh = Kg + (size_t)bh * T_ * HD_;
  const bf16_t* Vh = Vt + (size_t)bh * HD_ * T_;

  bf16x8 qfA[4], qfB[4];
#pragma unroll
  for (int kk = 0; kk < 4; ++kk) {
    qfA[kk] = *(const bf16x8*)(Qh + (size_t)(q0A + l15) * HD_ + kk * 32 + quad * 8);
    qfB[kk] = *(const bf16x8*)(Qh + (size_t)(q0B + l15) * HD_ + kk * 32 + quad * 8);
  }

  floatx4 oaccA[8] = {}, oaccB[8] = {};
  float l_A = 0.0f, l_B = 0.0f;

  union PU { bf16x4 v; long long u; };
  union PF { long long u[2]; bf16x8 v; };
  const int lo = ((lane & 16) << 1) + l15;  // (quad&1)*32 + l15

  auto stage = [&](int buf, int kt0) {
#pragma unroll
    for (int it = 0; it < 4; ++it) {
      int p = it * 4096 + tid * 16;
      int r = p >> 8;
      int cg = ((p >> 4) & 15) ^ (r & 15);
      async_copy16(Kh + (size_t)(kt0 + r) * HD_ + cg * 8, (char*)&Ks[buf][0][0] + p);
    }
#pragma unroll
    for (int it = 0; it < 4; ++it) {
      int p = it * 4096 + tid * 16;
      int r = p >> 7;
      int cg = ((p >> 4) & 7) ^ (r & 7);
      async_copy16(Vh + (size_t)r * T_ + kt0 + cg * 8, (char*)&Vs[buf][0][0] + p);
    }
  };

  auto step = [&](int buf, const bf16x8* qf, floatx4* oacc, float& l_i, int q0, int kt0,
                  bool mask) {
    floatx4 s[4] = {{}, {}, {}, {}};
#pragma unroll
    for (int st = 0; st < 4; ++st) {
#pragma unroll
      for (int kk = 0; kk < 4; ++kk) {
        bf16x8 kf = *(const bf16x8*)&Ks[buf][st * 16 + l15][(((kk * 4 + quad) ^ l15) & 15) * 8];
        s[st] = __builtin_amdgcn_mfma_f32_16x16x32_bf16(kf, qf[kk], s[st], 0, 0, 0);
      }
    }
    float ps = 0.0f;
    long long pu[4];
#pragma unroll
    for (int st = 0; st < 4; ++st) {
      PU t;
#pragma unroll
      for (int r = 0; r < 4; ++r) {
        float val = s[st][r];
        if (mask) {
          int kt = kt0 + st * 16 + quad * 4 + r;
          val = (kt <= q0 + l15) ? val : -3.0e38f;
        }
        float p = exp2f(val);
        ps += p;
        t.v[r] = (bf16_t)p;
      }
      pu[st] = t.u;
    }
    ps += __shfl_xor(ps, 16);
    ps += __shfl_xor(ps, 32);
    l_i += ps;
#pragma unroll
    for (int bb = 0; bb < 2; ++bb) {
      long long lo0 = __shfl(pu[2 * bb], lo);
      long long hi0 = __shfl(pu[2 * bb], lo + 16);
      long long lo1 = __shfl(pu[2 * bb + 1], lo);
      long long hi1 = __shfl(pu[2 * bb + 1], lo + 16);
      PF pf;
      pf.u[0] = (quad >= 2) ? lo1 : lo0;
      pf.u[1] = (quad >= 2) ? hi1 : hi0;
#pragma unroll
      for (int dt = 0; dt < 8; ++dt) {
        bf16x8 vf = *(const bf16x8*)&Vs[buf][dt * 16 + l15][(((bb * 4 + quad) ^ l15) & 7) * 8];
        oacc[dt] = __builtin_amdgcn_mfma_f32_16x16x32_bf16(pf.v, vf, oacc[dt], 0, 0, 0);
      }
    }
  };

  stage(0, 0);
  for (int ch = 0; ch < nchA; ++ch) {
    __syncthreads();
    if (ch + 1 < nchA) stage((ch + 1) & 1, (ch + 1) * 64);  // fly during compute
    const int kt0 = ch * 64;
    const int buf = ch & 1;
    step(buf, qfA, oaccA, l_A, q0A, kt0, ch == nchA - 1);
    if (ch < nchB) step(buf, qfB, oaccB, l_B, q0B, kt0, ch == nchB - 1);
  }

  float lrA[4], lrB[4];
#pragma unroll
  for (int r = 0; r < 4; ++r) {
    lrA[r] = __shfl(l_A, quad * 4 + r);
    lrB[r] = __shfl(l_B, quad * 4 + r);
  }
#pragma unroll
  for (int dt = 0; dt < 8; ++dt) {
#pragma unroll
    for (int r = 0; r < 4; ++r) {
      int d = dt * 16 + l15;
      int qa = q0A + quad * 4 + r;
      int qb = q0B + quad * 4 + r;
      O[((size_t)(b * T_ + qa)) * C_ + h * HD_ + d] = (bf16_t)(oaccA[dt][r] / lrA[r]);
      O[((size_t)(b * T_ + qb)) * C_ + h * HD_ + d] = (bf16_t)(oaccB[dt][r] / lrB[r]);
    }
  }
}

// ---------------- launch ----------------
extern "C" void kernel_launch(void* const* d_in, const int* in_sizes, int n_in,
                              void* d_out, int out_size, void* d_ws, size_t ws_size,
                              hipStream_t stream) {
  const float* x      = (const float*)d_in[0];
  const float* w_attn = (const float*)d_in[1];
  const float* b_attn = (const float*)d_in[2];
  const float* w_proj = (const float*)d_in[3];
  const float* b_proj = (const float*)d_in[4];
  float* out = (float*)d_out;

  char* p = (char*)d_ws;
  bf16_t* xb  = (bf16_t*)p; p += (size_t)4096 * 2048 * 2;      // x bf16 [B*T][C]
  bf16_t* waT = (bf16_t*)p; p += (size_t)6144 * 2048 * 2;      // w_attn^T bf16 [3C][C]
  bf16_t* wpT = (bf16_t*)p; p += (size_t)2048 * 2048 * 2;      // w_proj^T bf16 [C][C]
  bf16_t* Qb  = (bf16_t*)p; p += (size_t)32 * 2048 * 128 * 2;  // [B,H,T,hd] (pre-scaled)
  bf16_t* Kb  = (bf16_t*)p; p += (size_t)32 * 2048 * 128 * 2;  // [B,H,T,hd]
  bf16_t* Vb  = (bf16_t*)p; p += (size_t)32 * 2048 * 128 * 2;  // [B,H,hd,T] (transposed)
  bf16_t* Ob  = (bf16_t*)p; p += (size_t)4096 * 2048 * 2;      // attn out bf16 [B*T][C]

  cvt_f32_bf16<<<8192, 256, 0, stream>>>(x, xb, 2097152);
  transpose_cvt<<<dim3(6144 / 32, 2048 / 32), dim3(32, 8), 0, stream>>>(w_attn, waT, 2048, 6144);
  transpose_cvt<<<dim3(2048 / 32, 2048 / 32), dim3(32, 8), 0, stream>>>(w_proj, wpT, 2048, 2048);

  gemm_qkv<<<dim3(6144 / GBN, 4096 / GBM), 512, 0, stream>>>(
      xb, waT, b_attn, Qb, Kb, Vb, 2048);

  attn<<<dim3(16, 32), 256, 0, stream>>>(Qb, Kb, Vb, Ob);

  gemm_proj<<<dim3(2048 / TN, 4096 / TM), 256, 0, stream>>>(
      Ob, wpT, b_proj, out, 4096, 2048, 2048);
}